// Round 21
// baseline (1041.234 us; speedup 1.0000x reference)
//
#include <hip/hip_runtime.h>
#include <stdint.h>

#define B_DIM 512
#define I_DIM 128
#define H_DIM 128
#define NSTEP 511   // reference scans t = 0..T-2

typedef __attribute__((ext_vector_type(4))) float f32x4;
typedef _Float16 half2_t __attribute__((ext_vector_type(2)));
typedef _Float16 half8_t __attribute__((ext_vector_type(8)));

// Barrier draining ONLY LDS ops; global prefetches stay in flight across it.
#define BAR_LDS() asm volatile("s_waitcnt lgkmcnt(0)\n\ts_barrier" ::: "memory")
#define MFMA16(A, B, C) __builtin_amdgcn_mfma_f32_16x16x32_f16(A, B, C, 0, 0, 0)

__device__ __forceinline__ float frcp(float v) {
#if __has_builtin(__builtin_amdgcn_rcpf)
  return __builtin_amdgcn_rcpf(v);
#else
  return 1.f / v;
#endif
}
__device__ __forceinline__ unsigned pkrtz_u(float a, float b) {
#if __has_builtin(__builtin_amdgcn_cvt_pkrtz)
  return __builtin_bit_cast(unsigned, __builtin_amdgcn_cvt_pkrtz(a, b));
#else
  half2_t r; r.x = (_Float16)a; r.y = (_Float16)b;
  return __builtin_bit_cast(unsigned, r);
#endif
}

// ---------------------------------------------------------------------------
// Whole-chip latency-optimized GRU: 256 blocks x 2 batch rows, 384 threads =
// 6 waves. MFMA tiles carry only 2 valid rows (M-waste is free: we are
// latency-bound, not throughput-bound). Per-CU per-step work is ~8x smaller
// than r18's 16-row blocks: ~30KB LDS traffic, 6-wave barrier, ~1 gate-eval
// per active thread.
//   waves 0-3: h-role, 32 units each (2 col-tiles). 24 MFMA -> gate math on
//              lanes l4==0 (rows 0,1) -> 4 ds_write_b16.
//   wave 4:    x-role units 0-63 (4 col-tiles, 48 MFMA -> pp) + x staging.
//   wave 5:    x-role units 64-127 + decode/NLL via 4 MFMA vs W_dec frag.
// pp packs rows {0,1} as one f16-pair u32 per (gate,unit): 1.5KB/step.
// Both hT/xT buffers fully zeroed once; only rows 0,1 ever rewritten.
// One lgkm-only barrier per step; x prefetched 2 steps ahead in registers.
// ---------------------------------------------------------------------------
__global__ __launch_bounds__(384) void k_rec(
    const float* __restrict__ x, const float* __restrict__ gt,
    const float* __restrict__ Wih, const float* __restrict__ Whh,
    const float* __restrict__ bih, const float* __restrict__ bhh,
    const float* __restrict__ Wdec, const float* __restrict__ bdec,
    float* __restrict__ nll_part) {
  __shared__ __align__(16) _Float16 hT[2][16 * 128];  // 8 KB (rows 2-15 = 0)
  __shared__ __align__(16) _Float16 xT[2][16 * 128];  // 8 KB (rows 2-15 = 0)
  __shared__ unsigned pp[2][3][128];                  // 3 KB f16-pair preacts
  __shared__ float gl[NSTEP * 2];                     // 4 KB gt slice

  const int tid = threadIdx.x;
  const int lane = tid & 63;
  const int w = tid >> 6;                  // 0..5
  const int l15 = lane & 15, l4 = lane >> 4;
  const int row0 = blockIdx.x * 2;

  // ---- zero both h/x tile buffers (garbage rows must read as 0) ----
  {
    const uint4 z4 = {0u, 0u, 0u, 0u};
    for (int q = tid; q < 512; q += 384) {
      ((uint4*)hT)[q] = z4;
      ((uint4*)xT)[q] = z4;
    }
  }
  // ---- gt preload: gl[2s+r] = gt[s+1][row0+r] ----
  for (int q = tid; q < NSTEP * 2; q += 384)
    gl[q] = gt[(size_t)((q >> 1) + 1) * B_DIM + row0 + (q & 1)];

  if (w < 4) {
    // =========================== h-role ===========================
    const int u0 = 32 * w + l15;            // c=0 unit; c=1 unit = u0+16

    half8_t bh[2][3][4];
    float bhn[2];
#pragma unroll
    for (int c = 0; c < 2; ++c) {
      const int u = u0 + 16 * c;
#pragma unroll
      for (int g3 = 0; g3 < 3; ++g3)
#pragma unroll
        for (int ks = 0; ks < 4; ++ks) {
          const size_t off =
              (size_t)(g3 * H_DIM + u) * H_DIM + ks * 32 + l4 * 8;
          const float4 a = *(const float4*)(Whh + off);
          const float4 b = *(const float4*)(Whh + off + 4);
          half8_t v;
          v[0] = (_Float16)a.x; v[1] = (_Float16)a.y;
          v[2] = (_Float16)a.z; v[3] = (_Float16)a.w;
          v[4] = (_Float16)b.x; v[5] = (_Float16)b.y;
          v[6] = (_Float16)b.z; v[7] = (_Float16)b.w;
          bh[c][g3][ks] = v;
        }
      bhn[c] = bhh[2 * H_DIM + u];
    }
    float h_old[2][2] = {{0.f, 0.f}, {0.f, 0.f}};  // [c][row]

    __syncthreads();   // A: tiles zeroed, xT[0..1] staged
    __syncthreads();   // B: pp[0] ready

#pragma unroll 1
    for (int i = 0; i < NSTEP; ++i) {
      const char* hb = (const char*)hT[i & 1];
      half8_t ah[4];
#pragma unroll
      for (int ks = 0; ks < 4; ++ks)
        ah[ks] = *(const half8_t*)(hb + l15 * 256 +
                                   ((((ks << 2) | l4) ^ l15) << 4));
      // pp reads (broadcast across l4 groups); consumed after MFMAs
      const unsigned puR0 = pp[i & 1][0][u0];
      const unsigned puZ0 = pp[i & 1][1][u0];
      const unsigned puN0 = pp[i & 1][2][u0];
      const unsigned puR1 = pp[i & 1][0][u0 + 16];
      const unsigned puZ1 = pp[i & 1][1][u0 + 16];
      const unsigned puN1 = pp[i & 1][2][u0 + 16];

      f32x4 aR0 = (f32x4){0.f, 0.f, 0.f, 0.f}, aR1 = aR0;
      f32x4 aZ0 = aR0, aZ1 = aR0;
      f32x4 aN0 = (f32x4){bhn[0], bhn[0], bhn[0], bhn[0]};
      f32x4 aN1 = (f32x4){bhn[1], bhn[1], bhn[1], bhn[1]};
#pragma unroll
      for (int ks = 0; ks < 4; ++ks) {
        aR0 = MFMA16(ah[ks], bh[0][0][ks], aR0);
        aZ0 = MFMA16(ah[ks], bh[0][1][ks], aZ0);
        aN0 = MFMA16(ah[ks], bh[0][2][ks], aN0);
        aR1 = MFMA16(ah[ks], bh[1][0][ks], aR1);
        aZ1 = MFMA16(ah[ks], bh[1][1][ks], aZ1);
        aN1 = MFMA16(ah[ks], bh[1][2][ks], aN1);
      }

      // gate math on rows 0,1 (lanes l4==0); write hnew into other tile
      if (l4 == 0) {
        char* hw = (char*)hT[(i + 1) & 1];
#pragma unroll
        for (int c = 0; c < 2; ++c) {
          const int u = u0 + 16 * c;
          const half2_t pR = __builtin_bit_cast(half2_t, c ? puR1 : puR0);
          const half2_t pZ = __builtin_bit_cast(half2_t, c ? puZ1 : puZ0);
          const half2_t pN = __builtin_bit_cast(half2_t, c ? puN1 : puN0);
          const f32x4 aR = c ? aR1 : aR0;
          const f32x4 aZ = c ? aZ1 : aZ0;
          const f32x4 aN = c ? aN1 : aN0;
#pragma unroll
          for (int r = 0; r < 2; ++r) {
            const float pRr = (float)(r ? pR.y : pR.x);
            const float pZr = (float)(r ? pZ.y : pZ.x);
            const float pNr = (float)(r ? pN.y : pN.x);
            const float r_ = frcp(1.f + __expf(-(aR[r] + pRr)));
            const float z_ = frcp(1.f + __expf(-(aZ[r] + pZr)));
            const float a2 = pNr + r_ * aN[r];
            const float n_ = 1.f - 2.f * frcp(__expf(2.f * a2) + 1.f);
            const float hnew = n_ + z_ * (h_old[c][r] - n_);
            h_old[c][r] = hnew;
            *(_Float16*)(hw + r * 256 + (((u >> 3) ^ r) << 4) + (u & 7) * 2) =
                (_Float16)hnew;
          }
        }
      }
      BAR_LDS();
    }
  } else {
    // ======================= x-role (waves 4,5) =======================
    const int ub = (w - 4) * 64;            // unit base: 0 or 64

    half8_t bx[4][3][4];
    float brz0[4], brz1[4], bxn[4];
#pragma unroll
    for (int c = 0; c < 4; ++c) {
      const int u = ub + 16 * c + l15;
#pragma unroll
      for (int g3 = 0; g3 < 3; ++g3)
#pragma unroll
        for (int ks = 0; ks < 4; ++ks) {
          const size_t off =
              (size_t)(g3 * H_DIM + u) * H_DIM + ks * 32 + l4 * 8;
          const float4 a = *(const float4*)(Wih + off);
          const float4 b = *(const float4*)(Wih + off + 4);
          half8_t v;
          v[0] = (_Float16)a.x; v[1] = (_Float16)a.y;
          v[2] = (_Float16)a.z; v[3] = (_Float16)a.w;
          v[4] = (_Float16)b.x; v[5] = (_Float16)b.y;
          v[6] = (_Float16)b.z; v[7] = (_Float16)b.w;
          bx[c][g3][ks] = v;
        }
      brz0[c] = bih[u] + bhh[u];
      brz1[c] = bih[H_DIM + u] + bhh[H_DIM + u];
      bxn[c] = bih[2 * H_DIM + u];
    }
    // decode fragment + gt (wave 5 only uses them)
    half8_t wdB[4];
#pragma unroll
    for (int ks = 0; ks < 4; ++ks) {
      half8_t v;
#pragma unroll
      for (int j = 0; j < 8; ++j)
        v[j] = (l15 == 0) ? (_Float16)Wdec[ks * 32 + l4 * 8 + j] : (_Float16)0.f;
      wdB[ks] = v;
    }
    const float bd0 = bdec[0];
    float nllA[2] = {0.f, 0.f};

    // x staging identity (wave 4 only): lane covers 4 f32 = 8B f16
    const int sr = lane >> 5;               // row 0,1
    const int cq = lane & 31;               // float4 chunk
    const int sbyte = sr * 256 + (((cq >> 1) ^ sr) << 4) + (cq & 1) * 8;
    const size_t xlbase = ((size_t)(row0 + sr)) * I_DIM + 4 * cq;

    float4 xA = {0.f, 0.f, 0.f, 0.f};
    if (w == 4) {
#pragma unroll
      for (int t = 0; t < 2; ++t) {
        const float4 v = *(const float4*)&x[(size_t)t * B_DIM * I_DIM + xlbase];
        uint2 p;
        p.x = pkrtz_u(v.x, v.y);
        p.y = pkrtz_u(v.z, v.w);
        *(uint2*)((char*)xT[t] + sbyte) = p;
      }
      xA = *(const float4*)&x[(size_t)2 * B_DIM * I_DIM + xlbase];
    }
    __syncthreads();   // A: tiles zeroed + xT[0..1] staged

    // pp[0] from xT[0]
    {
      const char* xb = (const char*)xT[0];
      half8_t af[4];
#pragma unroll
      for (int ks = 0; ks < 4; ++ks)
        af[ks] = *(const half8_t*)(xb + l15 * 256 +
                                   ((((ks << 2) | l4) ^ l15) << 4));
#pragma unroll
      for (int c = 0; c < 4; ++c) {
        f32x4 aR = (f32x4){brz0[c], brz0[c], brz0[c], brz0[c]};
        f32x4 aZ = (f32x4){brz1[c], brz1[c], brz1[c], brz1[c]};
        f32x4 aN = (f32x4){bxn[c], bxn[c], bxn[c], bxn[c]};
#pragma unroll
        for (int ks = 0; ks < 4; ++ks) {
          aR = MFMA16(af[ks], bx[c][0][ks], aR);
          aZ = MFMA16(af[ks], bx[c][1][ks], aZ);
          aN = MFMA16(af[ks], bx[c][2][ks], aN);
        }
        if (l4 == 0) {
          const int u = ub + 16 * c + l15;
          pp[0][0][u] = pkrtz_u(aR[0], aR[1]);
          pp[0][1][u] = pkrtz_u(aZ[0], aZ[1]);
          pp[0][2][u] = pkrtz_u(aN[0], aN[1]);
        }
      }
    }
    __syncthreads();   // B: pp[0] ready

#pragma unroll 1
    for (int i = 0; i < NSTEP; ++i) {
      // pp for step i+1 from xT[(i+1)&1]
      const char* xb = (const char*)xT[(i + 1) & 1];
      half8_t af[4];
#pragma unroll
      for (int ks = 0; ks < 4; ++ks)
        af[ks] = *(const half8_t*)(xb + l15 * 256 +
                                   ((((ks << 2) | l4) ^ l15) << 4));
#pragma unroll
      for (int c = 0; c < 4; ++c) {
        f32x4 aR = (f32x4){brz0[c], brz0[c], brz0[c], brz0[c]};
        f32x4 aZ = (f32x4){brz1[c], brz1[c], brz1[c], brz1[c]};
        f32x4 aN = (f32x4){bxn[c], bxn[c], bxn[c], bxn[c]};
#pragma unroll
        for (int ks = 0; ks < 4; ++ks) {
          aR = MFMA16(af[ks], bx[c][0][ks], aR);
          aZ = MFMA16(af[ks], bx[c][1][ks], aZ);
          aN = MFMA16(af[ks], bx[c][2][ks], aN);
        }
        if (l4 == 0) {
          const int u = ub + 16 * c + l15;
          pp[(i + 1) & 1][0][u] = pkrtz_u(aR[0], aR[1]);
          pp[(i + 1) & 1][1][u] = pkrtz_u(aZ[0], aZ[1]);
          pp[(i + 1) & 1][2][u] = pkrtz_u(aN[0], aN[1]);
        }
      }

      if (w == 4) {
        // stage x(i+2) from xA; issue load for x(i+3)
        uint2 p;
        p.x = pkrtz_u(xA.x, xA.y);
        p.y = pkrtz_u(xA.z, xA.w);
        *(uint2*)((char*)xT[i & 1] + sbyte) = p;
        const size_t trow =
            (size_t)((i + 3 < 512) ? i + 3 : 511) * B_DIM * I_DIM;
        xA = *(const float4*)&x[trow + xlbase];
      } else if (i > 0) {
        // decode + NLL for h(i) vs gt[i] (hT[i&1] stable this interval)
        const char* hb = (const char*)hT[i & 1];
        half8_t dh[4];
#pragma unroll
        for (int ks = 0; ks < 4; ++ks)
          dh[ks] = *(const half8_t*)(hb + l15 * 256 +
                                     ((((ks << 2) | l4) ^ l15) << 4));
        f32x4 aD = (f32x4){0.f, 0.f, 0.f, 0.f};
#pragma unroll
        for (int ks = 0; ks < 4; ++ks) aD = MFMA16(dh[ks], wdB[ks], aD);
        if (lane == 0) {
#pragma unroll
          for (int r = 0; r < 2; ++r) {
            const float C = frcp(1.f + __expf(-(aD[r] + bd0)));
            const float g = gl[(i - 1) * 2 + r];
            nllA[r] -= g * __logf(C + 1e-4f) +
                       (1.f - g) * __logf(1.f - C + 1e-4f);
          }
        }
      }
      BAR_LDS();
    }

    // epilogue (wave 5): decode h(511) vs gt[511]; write per-row NLL
    if (w == 5) {
      const char* hb = (const char*)hT[NSTEP & 1];
      half8_t dh[4];
#pragma unroll
      for (int ks = 0; ks < 4; ++ks)
        dh[ks] = *(const half8_t*)(hb + l15 * 256 +
                                   ((((ks << 2) | l4) ^ l15) << 4));
      f32x4 aD = (f32x4){0.f, 0.f, 0.f, 0.f};
#pragma unroll
      for (int ks = 0; ks < 4; ++ks) aD = MFMA16(dh[ks], wdB[ks], aD);
      if (lane == 0) {
#pragma unroll
        for (int r = 0; r < 2; ++r) {
          const float C = frcp(1.f + __expf(-(aD[r] + bd0)));
          const float g = gl[(NSTEP - 1) * 2 + r];
          nllA[r] -= g * __logf(C + 1e-4f) +
                     (1.f - g) * __logf(1.f - C + 1e-4f);
          nll_part[row0 + r] = nllA[r];
        }
      }
    }
  }
}

// ---------------------------------------------------------------------------
__global__ __launch_bounds__(512) void k_fin(const float* __restrict__ nll_part,
                                             float* __restrict__ out) {
  __shared__ float red[8];
  const int tid = threadIdx.x;
  float v = nll_part[tid];
#pragma unroll
  for (int off = 32; off; off >>= 1) v += __shfl_down(v, off);
  if ((tid & 63) == 0) red[tid >> 6] = v;
  __syncthreads();
  if (tid == 0) {
    float s = 0.f;
#pragma unroll
    for (int i = 0; i < 8; ++i) s += red[i];
    out[0] = s * (1.f / (512.f * 512.f));
  }
}

// ---------------------------------------------------------------------------
extern "C" void kernel_launch(void* const* d_in, const int* in_sizes, int n_in,
                              void* d_out, int out_size, void* d_ws,
                              size_t ws_size, hipStream_t stream) {
  const float* x    = (const float*)d_in[0];
  const float* gt   = (const float*)d_in[1];
  const float* Wih  = (const float*)d_in[2];
  const float* Whh  = (const float*)d_in[3];
  const float* bih  = (const float*)d_in[4];
  const float* bhh  = (const float*)d_in[5];
  const float* Wdec = (const float*)d_in[6];
  const float* bdec = (const float*)d_in[7];

  float* nll_part = (float*)d_ws;  // 512 floats, each written exactly once

  k_rec<<<dim3(256), dim3(384), 0, stream>>>(
      x, gt, Wih, Whh, bih, bhh, Wdec, bdec, nll_part);
  k_fin<<<dim3(1), dim3(512), 0, stream>>>(nll_part, (float*)d_out);
}

// Round 22
// 423.433 us; speedup vs baseline: 2.4590x; 2.4590x over previous
//
#include <hip/hip_runtime.h>
#include <stdint.h>

#define B_DIM 512
#define I_DIM 128
#define H_DIM 128
#define NSTEP 511   // reference scans t = 0..T-2

typedef __attribute__((ext_vector_type(4))) float f32x4;
typedef _Float16 half2_t __attribute__((ext_vector_type(2)));
typedef _Float16 half8_t __attribute__((ext_vector_type(8)));

// Barrier draining ONLY LDS ops; global prefetches stay in flight across it.
#define BAR_LDS() asm volatile("s_waitcnt lgkmcnt(0)\n\ts_barrier" ::: "memory")
#define MFMA16(A, B, C) __builtin_amdgcn_mfma_f32_16x16x32_f16(A, B, C, 0, 0, 0)

__device__ __forceinline__ float frcp(float v) {
#if __has_builtin(__builtin_amdgcn_rcpf)
  return __builtin_amdgcn_rcpf(v);
#else
  return 1.f / v;
#endif
}
__device__ __forceinline__ unsigned pkrtz_u(float a, float b) {
#if __has_builtin(__builtin_amdgcn_cvt_pkrtz)
  return __builtin_bit_cast(unsigned, __builtin_amdgcn_cvt_pkrtz(a, b));
#else
  half2_t r; r.x = (_Float16)a; r.y = (_Float16)b;
  return __builtin_bit_cast(unsigned, r);
#endif
}

// ---------------------------------------------------------------------------
// Whole-chip latency-optimized GRU: 256 blocks x 2 batch rows, 512 threads =
// 8 waves (2/SIMD). r22 = r21 with the x-role register spill designed out:
// x-role is 4 waves x 2 col-tiles (96 weight VGPRs, same as h-role) instead
// of 2 waves x 4 tiles (192 VGPRs -> spilled at the 128-VGPR budget, r21's
// 35MB scratch traffic). MFMA tiles carry 2 valid rows; M-waste is free
// (latency-bound). waves 0-3 h-role (32 units each); waves 4-7 x-role (32
// units each); wave 4 stages x (2 steps ahead); wave 7 decode+NLL.
// pp packs rows {0,1} as f16-pair u32 per (gate,unit). One lgkm-only
// barrier per step. Extra sync after tile-zeroing closes r21's benign race.
// ---------------------------------------------------------------------------
__global__ __launch_bounds__(512, 1) void k_rec(
    const float* __restrict__ x, const float* __restrict__ gt,
    const float* __restrict__ Wih, const float* __restrict__ Whh,
    const float* __restrict__ bih, const float* __restrict__ bhh,
    const float* __restrict__ Wdec, const float* __restrict__ bdec,
    float* __restrict__ nll_part) {
  __shared__ __align__(16) _Float16 hT[2][16 * 128];  // 8 KB (rows 2-15 = 0)
  __shared__ __align__(16) _Float16 xT[2][16 * 128];  // 8 KB (rows 2-15 = 0)
  __shared__ unsigned pp[2][3][128];                  // 3 KB f16-pair preacts
  __shared__ float gl[NSTEP * 2];                     // 4 KB gt slice

  const int tid = threadIdx.x;
  const int lane = tid & 63;
  const int w = tid >> 6;                  // 0..7
  const int l15 = lane & 15, l4 = lane >> 4;
  const int row0 = blockIdx.x * 2;

  // ---- zero both h/x tile buffers (garbage rows must read as 0) ----
  {
    const uint4 z4 = {0u, 0u, 0u, 0u};
    ((uint4*)hT)[tid] = z4;
    ((uint4*)xT)[tid] = z4;
  }
  // ---- gt preload: gl[2s+r] = gt[s+1][row0+r] ----
  for (int q = tid; q < NSTEP * 2; q += 512)
    gl[q] = gt[(size_t)((q >> 1) + 1) * B_DIM + row0 + (q & 1)];
  __syncthreads();   // Z: tiles zeroed before any staging

  if (w < 4) {
    // =========================== h-role ===========================
    const int u0 = 32 * w + l15;            // c=0 unit; c=1 unit = u0+16

    half8_t bh[2][3][4];
    float bhn[2];
#pragma unroll
    for (int c = 0; c < 2; ++c) {
      const int u = u0 + 16 * c;
#pragma unroll
      for (int g3 = 0; g3 < 3; ++g3)
#pragma unroll
        for (int ks = 0; ks < 4; ++ks) {
          const size_t off =
              (size_t)(g3 * H_DIM + u) * H_DIM + ks * 32 + l4 * 8;
          const float4 a = *(const float4*)(Whh + off);
          const float4 b = *(const float4*)(Whh + off + 4);
          half8_t v;
          v[0] = (_Float16)a.x; v[1] = (_Float16)a.y;
          v[2] = (_Float16)a.z; v[3] = (_Float16)a.w;
          v[4] = (_Float16)b.x; v[5] = (_Float16)b.y;
          v[6] = (_Float16)b.z; v[7] = (_Float16)b.w;
          bh[c][g3][ks] = v;
        }
      bhn[c] = bhh[2 * H_DIM + u];
    }
    float h_old[2][2] = {{0.f, 0.f}, {0.f, 0.f}};  // [c][row]

    __syncthreads();   // A: xT[0..1] staged
    __syncthreads();   // B: pp[0] ready

#pragma unroll 1
    for (int i = 0; i < NSTEP; ++i) {
      const char* hb = (const char*)hT[i & 1];
      half8_t ah[4];
#pragma unroll
      for (int ks = 0; ks < 4; ++ks)
        ah[ks] = *(const half8_t*)(hb + l15 * 256 +
                                   ((((ks << 2) | l4) ^ l15) << 4));
      // pp reads issued early; consumed after the MFMA chain
      const unsigned puR0 = pp[i & 1][0][u0];
      const unsigned puZ0 = pp[i & 1][1][u0];
      const unsigned puN0 = pp[i & 1][2][u0];
      const unsigned puR1 = pp[i & 1][0][u0 + 16];
      const unsigned puZ1 = pp[i & 1][1][u0 + 16];
      const unsigned puN1 = pp[i & 1][2][u0 + 16];

      f32x4 aR0 = (f32x4){0.f, 0.f, 0.f, 0.f}, aR1 = aR0;
      f32x4 aZ0 = aR0, aZ1 = aR0;
      f32x4 aN0 = (f32x4){bhn[0], bhn[0], bhn[0], bhn[0]};
      f32x4 aN1 = (f32x4){bhn[1], bhn[1], bhn[1], bhn[1]};
#pragma unroll
      for (int ks = 0; ks < 4; ++ks) {
        aR0 = MFMA16(ah[ks], bh[0][0][ks], aR0);
        aZ0 = MFMA16(ah[ks], bh[0][1][ks], aZ0);
        aN0 = MFMA16(ah[ks], bh[0][2][ks], aN0);
        aR1 = MFMA16(ah[ks], bh[1][0][ks], aR1);
        aZ1 = MFMA16(ah[ks], bh[1][1][ks], aZ1);
        aN1 = MFMA16(ah[ks], bh[1][2][ks], aN1);
      }

      // gate math on rows 0,1 (lanes l4==0); write hnew into other tile
      if (l4 == 0) {
        char* hw = (char*)hT[(i + 1) & 1];
#pragma unroll
        for (int c = 0; c < 2; ++c) {
          const int u = u0 + 16 * c;
          const half2_t pR = __builtin_bit_cast(half2_t, c ? puR1 : puR0);
          const half2_t pZ = __builtin_bit_cast(half2_t, c ? puZ1 : puZ0);
          const half2_t pN = __builtin_bit_cast(half2_t, c ? puN1 : puN0);
          const f32x4 aR = c ? aR1 : aR0;
          const f32x4 aZ = c ? aZ1 : aZ0;
          const f32x4 aN = c ? aN1 : aN0;
#pragma unroll
          for (int r = 0; r < 2; ++r) {
            const float pRr = (float)(r ? pR.y : pR.x);
            const float pZr = (float)(r ? pZ.y : pZ.x);
            const float pNr = (float)(r ? pN.y : pN.x);
            const float r_ = frcp(1.f + __expf(-(aR[r] + pRr)));
            const float z_ = frcp(1.f + __expf(-(aZ[r] + pZr)));
            const float a2 = pNr + r_ * aN[r];
            const float n_ = 1.f - 2.f * frcp(__expf(2.f * a2) + 1.f);
            const float hnew = n_ + z_ * (h_old[c][r] - n_);
            h_old[c][r] = hnew;
            *(_Float16*)(hw + r * 256 + (((u >> 3) ^ r) << 4) + (u & 7) * 2) =
                (_Float16)hnew;
          }
        }
      }
      BAR_LDS();
    }
  } else {
    // ======================= x-role (waves 4..7) =======================
    const int wx = w - 4;                   // 0..3
    const int u0 = 32 * wx + l15;           // c=0 unit; c=1 unit = u0+16

    half8_t bx[2][3][4];
    float brz0[2], brz1[2], bxn[2];
#pragma unroll
    for (int c = 0; c < 2; ++c) {
      const int u = u0 + 16 * c;
#pragma unroll
      for (int g3 = 0; g3 < 3; ++g3)
#pragma unroll
        for (int ks = 0; ks < 4; ++ks) {
          const size_t off =
              (size_t)(g3 * H_DIM + u) * H_DIM + ks * 32 + l4 * 8;
          const float4 a = *(const float4*)(Wih + off);
          const float4 b = *(const float4*)(Wih + off + 4);
          half8_t v;
          v[0] = (_Float16)a.x; v[1] = (_Float16)a.y;
          v[2] = (_Float16)a.z; v[3] = (_Float16)a.w;
          v[4] = (_Float16)b.x; v[5] = (_Float16)b.y;
          v[6] = (_Float16)b.z; v[7] = (_Float16)b.w;
          bx[c][g3][ks] = v;
        }
      brz0[c] = bih[u] + bhh[u];
      brz1[c] = bih[H_DIM + u] + bhh[H_DIM + u];
      bxn[c] = bih[2 * H_DIM + u];
    }
    // decode fragment (wave 7 only uses it)
    half8_t wdB[4];
#pragma unroll
    for (int ks = 0; ks < 4; ++ks) {
      half8_t v;
#pragma unroll
      for (int j = 0; j < 8; ++j)
        v[j] = (l15 == 0) ? (_Float16)Wdec[ks * 32 + l4 * 8 + j] : (_Float16)0.f;
      wdB[ks] = v;
    }
    const float bd0 = bdec[0];
    float nllA[2] = {0.f, 0.f};

    // x staging identity (wave 4 only): lane covers 4 f32 = 8B f16
    const int sr = lane >> 5;               // row 0,1
    const int cq = lane & 31;               // float4 chunk
    const int sbyte = sr * 256 + (((cq >> 1) ^ sr) << 4) + (cq & 1) * 8;
    const size_t xlbase = ((size_t)(row0 + sr)) * I_DIM + 4 * cq;

    float4 xA = {0.f, 0.f, 0.f, 0.f};
    if (w == 4) {
#pragma unroll
      for (int t = 0; t < 2; ++t) {
        const float4 v = *(const float4*)&x[(size_t)t * B_DIM * I_DIM + xlbase];
        uint2 p;
        p.x = pkrtz_u(v.x, v.y);
        p.y = pkrtz_u(v.z, v.w);
        *(uint2*)((char*)xT[t] + sbyte) = p;
      }
      xA = *(const float4*)&x[(size_t)2 * B_DIM * I_DIM + xlbase];
    }
    __syncthreads();   // A: xT[0..1] staged

    // pp[0] from xT[0]
    {
      const char* xb = (const char*)xT[0];
      half8_t af[4];
#pragma unroll
      for (int ks = 0; ks < 4; ++ks)
        af[ks] = *(const half8_t*)(xb + l15 * 256 +
                                   ((((ks << 2) | l4) ^ l15) << 4));
#pragma unroll
      for (int c = 0; c < 2; ++c) {
        f32x4 aR = (f32x4){brz0[c], brz0[c], brz0[c], brz0[c]};
        f32x4 aZ = (f32x4){brz1[c], brz1[c], brz1[c], brz1[c]};
        f32x4 aN = (f32x4){bxn[c], bxn[c], bxn[c], bxn[c]};
#pragma unroll
        for (int ks = 0; ks < 4; ++ks) {
          aR = MFMA16(af[ks], bx[c][0][ks], aR);
          aZ = MFMA16(af[ks], bx[c][1][ks], aZ);
          aN = MFMA16(af[ks], bx[c][2][ks], aN);
        }
        if (l4 == 0) {
          const int u = u0 + 16 * c;
          pp[0][0][u] = pkrtz_u(aR[0], aR[1]);
          pp[0][1][u] = pkrtz_u(aZ[0], aZ[1]);
          pp[0][2][u] = pkrtz_u(aN[0], aN[1]);
        }
      }
    }
    __syncthreads();   // B: pp[0] ready

#pragma unroll 1
    for (int i = 0; i < NSTEP; ++i) {
      // pp for step i+1 from xT[(i+1)&1]
      const char* xb = (const char*)xT[(i + 1) & 1];
      half8_t af[4];
#pragma unroll
      for (int ks = 0; ks < 4; ++ks)
        af[ks] = *(const half8_t*)(xb + l15 * 256 +
                                   ((((ks << 2) | l4) ^ l15) << 4));
#pragma unroll
      for (int c = 0; c < 2; ++c) {
        f32x4 aR = (f32x4){brz0[c], brz0[c], brz0[c], brz0[c]};
        f32x4 aZ = (f32x4){brz1[c], brz1[c], brz1[c], brz1[c]};
        f32x4 aN = (f32x4){bxn[c], bxn[c], bxn[c], bxn[c]};
#pragma unroll
        for (int ks = 0; ks < 4; ++ks) {
          aR = MFMA16(af[ks], bx[c][0][ks], aR);
          aZ = MFMA16(af[ks], bx[c][1][ks], aZ);
          aN = MFMA16(af[ks], bx[c][2][ks], aN);
        }
        if (l4 == 0) {
          const int u = u0 + 16 * c;
          pp[(i + 1) & 1][0][u] = pkrtz_u(aR[0], aR[1]);
          pp[(i + 1) & 1][1][u] = pkrtz_u(aZ[0], aZ[1]);
          pp[(i + 1) & 1][2][u] = pkrtz_u(aN[0], aN[1]);
        }
      }

      if (w == 4) {
        // stage x(i+2) from xA; issue load for x(i+3)
        uint2 p;
        p.x = pkrtz_u(xA.x, xA.y);
        p.y = pkrtz_u(xA.z, xA.w);
        *(uint2*)((char*)xT[i & 1] + sbyte) = p;
        const size_t trow =
            (size_t)((i + 3 < 512) ? i + 3 : 511) * B_DIM * I_DIM;
        xA = *(const float4*)&x[trow + xlbase];
      } else if (w == 7 && i > 0) {
        // decode + NLL for h(i) vs gt[i] (hT[i&1] stable this interval)
        const char* hb = (const char*)hT[i & 1];
        half8_t dh[4];
#pragma unroll
        for (int ks = 0; ks < 4; ++ks)
          dh[ks] = *(const half8_t*)(hb + l15 * 256 +
                                     ((((ks << 2) | l4) ^ l15) << 4));
        f32x4 aD = (f32x4){0.f, 0.f, 0.f, 0.f};
#pragma unroll
        for (int ks = 0; ks < 4; ++ks) aD = MFMA16(dh[ks], wdB[ks], aD);
        if (lane == 0) {
#pragma unroll
          for (int r = 0; r < 2; ++r) {
            const float C = frcp(1.f + __expf(-(aD[r] + bd0)));
            const float g = gl[(i - 1) * 2 + r];
            nllA[r] -= g * __logf(C + 1e-4f) +
                       (1.f - g) * __logf(1.f - C + 1e-4f);
          }
        }
      }
      BAR_LDS();
    }

    // epilogue (wave 7): decode h(511) vs gt[511]; write per-row NLL
    if (w == 7) {
      const char* hb = (const char*)hT[NSTEP & 1];
      half8_t dh[4];
#pragma unroll
      for (int ks = 0; ks < 4; ++ks)
        dh[ks] = *(const half8_t*)(hb + l15 * 256 +
                                   ((((ks << 2) | l4) ^ l15) << 4));
      f32x4 aD = (f32x4){0.f, 0.f, 0.f, 0.f};
#pragma unroll
      for (int ks = 0; ks < 4; ++ks) aD = MFMA16(dh[ks], wdB[ks], aD);
      if (lane == 0) {
#pragma unroll
        for (int r = 0; r < 2; ++r) {
          const float C = frcp(1.f + __expf(-(aD[r] + bd0)));
          const float g = gl[(NSTEP - 1) * 2 + r];
          nllA[r] -= g * __logf(C + 1e-4f) +
                     (1.f - g) * __logf(1.f - C + 1e-4f);
          nll_part[row0 + r] = nllA[r];
        }
      }
    }
  }
}

// ---------------------------------------------------------------------------
__global__ __launch_bounds__(512) void k_fin(const float* __restrict__ nll_part,
                                             float* __restrict__ out) {
  __shared__ float red[8];
  const int tid = threadIdx.x;
  float v = nll_part[tid];
#pragma unroll
  for (int off = 32; off; off >>= 1) v += __shfl_down(v, off);
  if ((tid & 63) == 0) red[tid >> 6] = v;
  __syncthreads();
  if (tid == 0) {
    float s = 0.f;
#pragma unroll
    for (int i = 0; i < 8; ++i) s += red[i];
    out[0] = s * (1.f / (512.f * 512.f));
  }
}

// ---------------------------------------------------------------------------
extern "C" void kernel_launch(void* const* d_in, const int* in_sizes, int n_in,
                              void* d_out, int out_size, void* d_ws,
                              size_t ws_size, hipStream_t stream) {
  const float* x    = (const float*)d_in[0];
  const float* gt   = (const float*)d_in[1];
  const float* Wih  = (const float*)d_in[2];
  const float* Whh  = (const float*)d_in[3];
  const float* bih  = (const float*)d_in[4];
  const float* bhh  = (const float*)d_in[5];
  const float* Wdec = (const float*)d_in[6];
  const float* bdec = (const float*)d_in[7];

  float* nll_part = (float*)d_ws;  // 512 floats, each written exactly once

  k_rec<<<dim3(256), dim3(512), 0, stream>>>(
      x, gt, Wih, Whh, bih, bhh, Wdec, bdec, nll_part);
  k_fin<<<dim3(1), dim3(512), 0, stream>>>(nll_part, (float*)d_out);
}